// Round 7
// baseline (135.269 us; speedup 1.0000x reference)
//
#include <hip/hip_runtime.h>
#include <hip/hip_bf16.h>

#define G_ 8
#define GIN_ 256
#define GOUT_ 256
#define NROWS_ 8192
#define LDX_ 2048   // = G_*GIN_ = row stride of x and out

typedef __attribute__((ext_vector_type(4))) float f32x4;
typedef __attribute__((ext_vector_type(8))) short bf16x8;

// ---------------------------------------------------------------------------
// Prep: W [G][GIN=k 256][GOUT=col 256] f32 -> WtB fragment-tiled bf16:
//   granule(g, c, cb, c16, quad) = W[g][k = c*32+quad*8 .. +8][col = cb*16+c16]
//   element offset = g*65536 + (c*16+cb)*512 + c16*32 + quad*8
// A wave's B-frag load (16 cols x 4 quads x 16B) is ONE contiguous 1 KB.
// (unchanged — harness-verified)
// ---------------------------------------------------------------------------
__global__ __launch_bounds__(256) void wprep_kernel(const float* __restrict__ W,
                                                    __hip_bfloat16* __restrict__ Wt) {
    __shared__ float tile[64][65];   // +1 pad
    const int bid = blockIdx.x;
    const int g  = bid >> 4;
    const int kt = (bid >> 2) & 3;   // k-tile (64 wide)
    const int ct = bid & 3;          // col-tile (64 wide)
    const float* Wg = W + g * (GIN_ * GOUT_);
    __hip_bfloat16* Wo = Wt + (size_t)g * (GIN_ * GOUT_);
    const int lane_o = threadIdx.x & 63;   // col within tile
    const int sub    = threadIdx.x >> 6;   // 0..3
#pragma unroll
    for (int r = 0; r < 16; ++r) {
        int i = r * 4 + sub;               // k within tile
        tile[i][lane_o] = Wg[(kt * 64 + i) * GOUT_ + ct * 64 + lane_o];
    }
    __syncthreads();
    const int col = threadIdx.x & 63;
    const int kgb = threadIdx.x >> 6;      // 0..3
#pragma unroll
    for (int h = 0; h < 2; ++h) {
        const int kg    = kgb + h * 4;     // 0..7: granule-of-8k in 64-k tile
        const int kglob = kt * 64 + kg * 8;
        const int c     = kglob >> 5;      // k-chunk 0..7
        const int quad  = (kglob >> 3) & 3;
        const int colg  = ct * 64 + col;
        const int cb    = colg >> 4;
        const int c16   = colg & 15;
        union { __hip_bfloat16 hh[8]; bf16x8 v; } cv;
#pragma unroll
        for (int j = 0; j < 8; ++j)
            cv.hh[j] = __float2bfloat16(tile[kg * 8 + j][col]);
        *(bf16x8*)(Wo + (size_t)(c * 16 + cb) * 512 + c16 * 32 + quad * 8) = cv.v;
    }
}

__device__ __forceinline__ bf16x8 cvt8(const f32x4 a, const f32x4 b) {
    union { __hip_bfloat16 h[8]; bf16x8 v; } u;
    u.h[0] = __float2bfloat16(a.x); u.h[1] = __float2bfloat16(a.y);
    u.h[2] = __float2bfloat16(a.z); u.h[3] = __float2bfloat16(a.w);
    u.h[4] = __float2bfloat16(b.x); u.h[5] = __float2bfloat16(b.y);
    u.h[6] = __float2bfloat16(b.z); u.h[7] = __float2bfloat16(b.w);
    return u.v;
}

// ---------------------------------------------------------------------------
// Main fused kernel — R4 structure + DMA x-staging (R7).
//  R4/R6 smoking gun: allocator pins 24-32 VGPRs, so the x staging path
//  (global->VGPR->cvt->ds_write) serializes: ~2 of 4 loads in flight, cvt+
//  ds_write+waits on every wave's pre-barrier critical path. Every barrier-
//  staged variant lands at ~42us while the harness's own fill kernel does
//  6.5 TB/s. Remedy per guide Common-mistake #1: __builtin_amdgcn_global_
//  load_lds width=16 — zero dest VGPRs, all staging requests of all 8
//  waves in flight at issue; f32 lands raw in LDS, cvt moves to the read
//  side (identical numerics: same RNE cvt per element).
//  Swizzle per rule #21 (both-sides-or-neither): LINEAR LDS dest +
//  INVERSE-swizzled global source + swizzled read: 16B-granule ^= (row&7).
//  Read-conflict math: bank-group = (q*2 ^ (lm&7))&7 -> uniform 8 lanes
//  per 4-bank group = b128 floor, no extra conflict.
//  One vmcnt(0)+barrier per block (m97 pattern). Everything else == R4.
// Grid: 8 g x 256 rowblocks = 2048 blocks; bid&7 = g keeps Wt[g] XCD-local.
// ---------------------------------------------------------------------------
__global__ __launch_bounds__(512, 8) void gkan_kernel(const float* __restrict__ x,
                                                      const __hip_bfloat16* __restrict__ Wt,
                                                      const float* __restrict__ bias,
                                                      const float* __restrict__ pc,
                                                      const float* __restrict__ qc,
                                                      float* __restrict__ out) {
    __shared__ __align__(16) float As[32 * 256];   // 32 KB raw f32 slab, LINEAR

    const int bid  = blockIdx.x;
    const int g    = bid & 7;
    const int row0 = (bid >> 3) * 32;

    const int t    = threadIdx.x;
    const int wave = t >> 6;             // 0..7 -> cols [wave*32, +32)
    const int lane = t & 63;
    const int lm   = lane & 15;
    const int q    = lane >> 4;

    // ---- x slab staging: 4x global_load_lds(16B) per thread, issue-and-forget.
    // Round r: wave w stages row r*8+w; lane l covers LDS 16B-slot l of that
    // row; source granule = l ^ (row&7) = l ^ w  (inverse swizzle at source).
    {
        const float* xrow = x + (size_t)row0 * LDX_ + g * GIN_;
#pragma unroll
        for (int r = 0; r < 4; ++r) {
            const int row  = r * 8 + wave;
            const int gidx = lane ^ wave;             // (row&7) == wave
            const float* src = xrow + (size_t)row * LDX_ + gidx * 4;
            __builtin_amdgcn_global_load_lds(
                (const __attribute__((address_space(1))) void*)src,
                (__attribute__((address_space(3))) void*)((char*)As + r * 8192 + t * 16),
                16, 0, 0);
        }
    }

    // ---- drain staging DMA, then barrier (once per block) ----
    asm volatile("s_waitcnt vmcnt(0) lgkmcnt(0)\n\ts_barrier" ::: "memory");

    // ---- K-loop: per chunk, 2 B-frags from L2 + 2 A-frags (f32, cvt) + 4 MFMA
    f32x4 acc[2][2] = {};
    const __hip_bfloat16* bp = Wt + (size_t)g * (GIN_ * GOUT_)
                                  + (wave * 2) * 512 + lm * 32 + q * 8;
#pragma unroll 1
    for (int c = 0; c < 8; ++c) {
        const bf16x8 bf0 = *(const bf16x8*)(bp);         // nt=0
        const bf16x8 bf1 = *(const bf16x8*)(bp + 512);   // nt=1
        const int s0 = c * 8 + q * 2;
        bf16x8 af[2];
#pragma unroll
        for (int mt = 0; mt < 2; ++mt) {
            const int rr = mt * 16 + lm;
            const f32x4 lo = *(const f32x4*)(As + rr * 256 + ((s0 ^ (lm & 7)) * 4));
            const f32x4 hi = *(const f32x4*)(As + rr * 256 + (((s0 + 1) ^ (lm & 7)) * 4));
            af[mt] = cvt8(lo, hi);
        }
        acc[0][0] = __builtin_amdgcn_mfma_f32_16x16x32_bf16(af[0], bf0, acc[0][0], 0, 0, 0);
        acc[0][1] = __builtin_amdgcn_mfma_f32_16x16x32_bf16(af[0], bf1, acc[0][1], 0, 0, 0);
        acc[1][0] = __builtin_amdgcn_mfma_f32_16x16x32_bf16(af[1], bf0, acc[1][0], 0, 0, 0);
        acc[1][1] = __builtin_amdgcn_mfma_f32_16x16x32_bf16(af[1], bf1, acc[1][1], 0, 0, 0);
        bp += 16 * 512;    // next k-chunk (16 col-blocks ahead)
    }

    // ---- epilogue consts loaded HERE (not live during the loop) ----
    const float p0 = pc[g * 4 + 0], p1 = pc[g * 4 + 1];
    const float p2 = pc[g * 4 + 2], p3 = pc[g * 4 + 3];
    const float q0 = qc[g * 3 + 0], q1 = qc[g * 3 + 1], q2 = qc[g * 3 + 2];
    float bb[2];
#pragma unroll
    for (int nt = 0; nt < 2; ++nt)
        bb[nt] = bias[g * GOUT_ + wave * 32 + nt * 16 + lm];

    // ---- epilogue: bias + rational, coalesced stores ----
#pragma unroll
    for (int nt = 0; nt < 2; ++nt) {
        const int col = g * GOUT_ + wave * 32 + nt * 16 + lm;
#pragma unroll
        for (int mt = 0; mt < 2; ++mt)
#pragma unroll
            for (int r = 0; r < 4; ++r) {
                const int row_o = row0 + mt * 16 + q * 4 + r;
                const float y   = acc[mt][nt][r] + bb[nt];
                const float num = p0 + y * (p1 + y * (p2 + y * p3));
                const float den = 1.0f + fabsf(y * (q0 + y * (q1 + y * q2)));
                out[(size_t)row_o * LDX_ + col] = num * __builtin_amdgcn_rcpf(den);
            }
    }
}

extern "C" void kernel_launch(void* const* d_in, const int* in_sizes, int n_in,
                              void* d_out, int out_size, void* d_ws, size_t ws_size,
                              hipStream_t stream) {
    const float* x = (const float*)d_in[0];
    const float* W = (const float*)d_in[1];
    const float* b = (const float*)d_in[2];
    const float* p = (const float*)d_in[3];
    const float* q = (const float*)d_in[4];
    float* out = (float*)d_out;

    __hip_bfloat16* Wt = (__hip_bfloat16*)d_ws;   // 1 MiB fragment-tiled bf16 W

    wprep_kernel<<<128, 256, 0, stream>>>(W, Wt);
    gkan_kernel<<<2048, 512, 0, stream>>>(x, Wt, b, p, q, out);
}

// Round 8
// 134.393 us; speedup vs baseline: 1.0065x; 1.0065x over previous
//
#include <hip/hip_runtime.h>
#include <hip/hip_bf16.h>

#define G_ 8
#define GIN_ 256
#define GOUT_ 256
#define NROWS_ 8192
#define LDX_ 2048   // = G_*GIN_ = row stride of x and out

typedef __attribute__((ext_vector_type(4))) float f32x4;
typedef __attribute__((ext_vector_type(8))) short bf16x8;

// ---------------------------------------------------------------------------
// Prep: W [G][GIN=k 256][GOUT=col 256] f32 -> WtB fragment-tiled bf16:
//   granule(g, c, cb, c16, quad) = W[g][k = c*32+quad*8 .. +8][col = cb*16+c16]
//   element offset = g*65536 + (c*16+cb)*512 + c16*32 + quad*8
// A wave's B-frag load (16 cols x 4 quads x 16B) is ONE contiguous 1 KB.
// (unchanged — harness-verified)
// ---------------------------------------------------------------------------
__global__ __launch_bounds__(256) void wprep_kernel(const float* __restrict__ W,
                                                    __hip_bfloat16* __restrict__ Wt) {
    __shared__ float tile[64][65];   // +1 pad
    const int bid = blockIdx.x;
    const int g  = bid >> 4;
    const int kt = (bid >> 2) & 3;   // k-tile (64 wide)
    const int ct = bid & 3;          // col-tile (64 wide)
    const float* Wg = W + g * (GIN_ * GOUT_);
    __hip_bfloat16* Wo = Wt + (size_t)g * (GIN_ * GOUT_);
    const int lane_o = threadIdx.x & 63;   // col within tile
    const int sub    = threadIdx.x >> 6;   // 0..3
#pragma unroll
    for (int r = 0; r < 16; ++r) {
        int i = r * 4 + sub;               // k within tile
        tile[i][lane_o] = Wg[(kt * 64 + i) * GOUT_ + ct * 64 + lane_o];
    }
    __syncthreads();
    const int col = threadIdx.x & 63;
    const int kgb = threadIdx.x >> 6;      // 0..3
#pragma unroll
    for (int h = 0; h < 2; ++h) {
        const int kg    = kgb + h * 4;     // 0..7: granule-of-8k in 64-k tile
        const int kglob = kt * 64 + kg * 8;
        const int c     = kglob >> 5;      // k-chunk 0..7
        const int quad  = (kglob >> 3) & 3;
        const int colg  = ct * 64 + col;
        const int cb    = colg >> 4;
        const int c16   = colg & 15;
        union { __hip_bfloat16 hh[8]; bf16x8 v; } cv;
#pragma unroll
        for (int j = 0; j < 8; ++j)
            cv.hh[j] = __float2bfloat16(tile[kg * 8 + j][col]);
        *(bf16x8*)(Wo + (size_t)(c * 16 + cb) * 512 + c16 * 32 + quad * 8) = cv.v;
    }
}

__device__ __forceinline__ bf16x8 cvt8(const f32x4 a, const f32x4 b) {
    union { __hip_bfloat16 h[8]; bf16x8 v; } u;
    u.h[0] = __float2bfloat16(a.x); u.h[1] = __float2bfloat16(a.y);
    u.h[2] = __float2bfloat16(a.z); u.h[3] = __float2bfloat16(a.w);
    u.h[4] = __float2bfloat16(b.x); u.h[5] = __float2bfloat16(b.y);
    u.h[6] = __float2bfloat16(b.z); u.h[7] = __float2bfloat16(b.w);
    return u.v;
}

// ---------------------------------------------------------------------------
// Main fused kernel — R7 + VECTORIZED STORE PATH via MFMA operand swap (R8).
//  Trace evidence: every 42-µs variant drains WRITE at exactly 1.56 TB/s
//  while the harness's fillBufferAligned in the SAME trace writes 6.3 TB/s.
//  Difference: fill uses dwordx4 (1 KB/wave-instr); we issued 16 scalar
//  dword stores/thread (256 B/wave-instr, 4 scattered 64B segments each).
//  Hypothesis: store-ISSUE/coalescer occupancy per instruction is the wall,
//  not write byte-BW.
//  Fix: mfma operand layouts are lane-symmetric, so mfma(W_frag, x_frag)
//  yields the TRANSPOSED C layout: lane lm = out-row, reg r = 4 CONSECUTIVE
//  out-cols. Epilogue becomes 4x global_store_dwordx4 per thread (4x fewer
//  store instrs, 4x payload). Same products, same bias values (f32x4 load),
//  same rational math -> identical numerics. Everything else == R7:
//  DMA x-staging (global_load_lds w=16, zero dest VGPRs, inverse-swizzled
//  source + swizzled read), one vmcnt(0)+barrier, rolled B-stream K-loop.
// Grid: 8 g x 256 rowblocks = 2048 blocks; bid&7 = g keeps Wt[g] XCD-local.
// ---------------------------------------------------------------------------
__global__ __launch_bounds__(512, 8) void gkan_kernel(const float* __restrict__ x,
                                                      const __hip_bfloat16* __restrict__ Wt,
                                                      const float* __restrict__ bias,
                                                      const float* __restrict__ pc,
                                                      const float* __restrict__ qc,
                                                      float* __restrict__ out) {
    __shared__ __align__(16) float As[32 * 256];   // 32 KB raw f32 slab, LINEAR

    const int bid  = blockIdx.x;
    const int g    = bid & 7;
    const int row0 = (bid >> 3) * 32;

    const int t    = threadIdx.x;
    const int wave = t >> 6;             // 0..7 -> cols [wave*32, +32)
    const int lane = t & 63;
    const int lm   = lane & 15;
    const int q    = lane >> 4;

    // ---- x slab staging: 4x global_load_lds(16B) per thread, issue-and-forget.
    // Round r: wave w stages row r*8+w; lane l covers LDS 16B-slot l of that
    // row; source granule = l ^ (row&7) = l ^ w  (inverse swizzle at source).
    {
        const float* xrow = x + (size_t)row0 * LDX_ + g * GIN_;
#pragma unroll
        for (int r = 0; r < 4; ++r) {
            const int row  = r * 8 + wave;
            const int gidx = lane ^ wave;             // (row&7) == wave
            const float* src = xrow + (size_t)row * LDX_ + gidx * 4;
            __builtin_amdgcn_global_load_lds(
                (const __attribute__((address_space(1))) void*)src,
                (__attribute__((address_space(3))) void*)((char*)As + r * 8192 + t * 16),
                16, 0, 0);
        }
    }

    // ---- drain staging DMA, then barrier (once per block) ----
    asm volatile("s_waitcnt vmcnt(0) lgkmcnt(0)\n\ts_barrier" ::: "memory");

    // ---- K-loop: per chunk, 2 B-frags from L2 + 2 A-frags (f32, cvt) + 4 MFMA
    // OPERAND SWAP: A-slot = W frag, B-slot = x frag -> transposed C layout.
    f32x4 acc[2][2] = {};   // acc[mt = x-row-block][nt = W-col-block]
    const __hip_bfloat16* bp = Wt + (size_t)g * (GIN_ * GOUT_)
                                  + (wave * 2) * 512 + lm * 32 + q * 8;
#pragma unroll 1
    for (int c = 0; c < 8; ++c) {
        const bf16x8 bf0 = *(const bf16x8*)(bp);         // nt=0 (W cols 0..15)
        const bf16x8 bf1 = *(const bf16x8*)(bp + 512);   // nt=1 (W cols 16..31)
        const int s0 = c * 8 + q * 2;
        bf16x8 af[2];
#pragma unroll
        for (int mt = 0; mt < 2; ++mt) {
            const int rr = mt * 16 + lm;
            const f32x4 lo = *(const f32x4*)(As + rr * 256 + ((s0 ^ (lm & 7)) * 4));
            const f32x4 hi = *(const f32x4*)(As + rr * 256 + (((s0 + 1) ^ (lm & 7)) * 4));
            af[mt] = cvt8(lo, hi);
        }
        acc[0][0] = __builtin_amdgcn_mfma_f32_16x16x32_bf16(bf0, af[0], acc[0][0], 0, 0, 0);
        acc[0][1] = __builtin_amdgcn_mfma_f32_16x16x32_bf16(bf1, af[0], acc[0][1], 0, 0, 0);
        acc[1][0] = __builtin_amdgcn_mfma_f32_16x16x32_bf16(bf0, af[1], acc[1][0], 0, 0, 0);
        acc[1][1] = __builtin_amdgcn_mfma_f32_16x16x32_bf16(bf1, af[1], acc[1][1], 0, 0, 0);
        bp += 16 * 512;    // next k-chunk (16 col-blocks ahead)
    }

    // ---- epilogue consts loaded HERE (not live during the loop) ----
    const float p0 = pc[g * 4 + 0], p1 = pc[g * 4 + 1];
    const float p2 = pc[g * 4 + 2], p3 = pc[g * 4 + 3];
    const float q0 = qc[g * 3 + 0], q1 = qc[g * 3 + 1], q2 = qc[g * 3 + 2];

    // ---- epilogue: transposed-C layout -> lane lm = out-row,
    //      reg r = 4 consecutive cols. ONE dwordx4 store per (mt,nt). ----
#pragma unroll
    for (int mt = 0; mt < 2; ++mt) {
        const int row_o = row0 + mt * 16 + lm;
#pragma unroll
        for (int nt = 0; nt < 2; ++nt) {
            const int col0 = g * GOUT_ + wave * 32 + nt * 16 + q * 4;
            const f32x4 bb4 = *(const f32x4*)(bias + col0);
            f32x4 o;
#pragma unroll
            for (int r = 0; r < 4; ++r) {
                const float y   = acc[mt][nt][r] + bb4[r];
                const float num = p0 + y * (p1 + y * (p2 + y * p3));
                const float den = 1.0f + fabsf(y * (q0 + y * (q1 + y * q2)));
                o[r] = num * __builtin_amdgcn_rcpf(den);
            }
            *(f32x4*)(out + (size_t)row_o * LDX_ + col0) = o;
        }
    }
}

extern "C" void kernel_launch(void* const* d_in, const int* in_sizes, int n_in,
                              void* d_out, int out_size, void* d_ws, size_t ws_size,
                              hipStream_t stream) {
    const float* x = (const float*)d_in[0];
    const float* W = (const float*)d_in[1];
    const float* b = (const float*)d_in[2];
    const float* p = (const float*)d_in[3];
    const float* q = (const float*)d_in[4];
    float* out = (float*)d_out;

    __hip_bfloat16* Wt = (__hip_bfloat16*)d_ws;   // 1 MiB fragment-tiled bf16 W

    wprep_kernel<<<128, 256, 0, stream>>>(W, Wt);
    gkan_kernel<<<2048, 512, 0, stream>>>(x, Wt, b, p, q, out);
}

// Round 9
// 134.060 us; speedup vs baseline: 1.0090x; 1.0025x over previous
//
#include <hip/hip_runtime.h>
#include <hip/hip_bf16.h>

#define G_ 8
#define GIN_ 256
#define GOUT_ 256
#define NROWS_ 8192
#define LDX_ 2048   // = G_*GIN_ = row stride of x and out

typedef __attribute__((ext_vector_type(4))) float f32x4;
typedef __attribute__((ext_vector_type(8))) short bf16x8;

// ---------------------------------------------------------------------------
// Prep: W [G][GIN=k 256][GOUT=col 256] f32 -> WtB fragment-tiled bf16:
//   granule(g, c, cb, c16, quad) = W[g][k = c*32+quad*8 .. +8][col = cb*16+c16]
//   element offset = g*65536 + (c*16+cb)*512 + c16*32 + quad*8
// A wave's B-frag load (16 cols x 4 quads x 16B) is ONE contiguous 1 KB.
// (unchanged — harness-verified)
// ---------------------------------------------------------------------------
__global__ __launch_bounds__(256) void wprep_kernel(const float* __restrict__ W,
                                                    __hip_bfloat16* __restrict__ Wt) {
    __shared__ float tile[64][65];   // +1 pad
    const int bid = blockIdx.x;
    const int g  = bid >> 4;
    const int kt = (bid >> 2) & 3;   // k-tile (64 wide)
    const int ct = bid & 3;          // col-tile (64 wide)
    const float* Wg = W + g * (GIN_ * GOUT_);
    __hip_bfloat16* Wo = Wt + (size_t)g * (GIN_ * GOUT_);
    const int lane_o = threadIdx.x & 63;   // col within tile
    const int sub    = threadIdx.x >> 6;   // 0..3
#pragma unroll
    for (int r = 0; r < 16; ++r) {
        int i = r * 4 + sub;               // k within tile
        tile[i][lane_o] = Wg[(kt * 64 + i) * GOUT_ + ct * 64 + lane_o];
    }
    __syncthreads();
    const int col = threadIdx.x & 63;
    const int kgb = threadIdx.x >> 6;      // 0..3
#pragma unroll
    for (int h = 0; h < 2; ++h) {
        const int kg    = kgb + h * 4;     // 0..7: granule-of-8k in 64-k tile
        const int kglob = kt * 64 + kg * 8;
        const int c     = kglob >> 5;      // k-chunk 0..7
        const int quad  = (kglob >> 3) & 3;
        const int colg  = ct * 64 + col;
        const int cb    = colg >> 4;
        const int c16   = colg & 15;
        union { __hip_bfloat16 hh[8]; bf16x8 v; } cv;
#pragma unroll
        for (int j = 0; j < 8; ++j)
            cv.hh[j] = __float2bfloat16(tile[kg * 8 + j][col]);
        *(bf16x8*)(Wo + (size_t)(c * 16 + cb) * 512 + c16 * 32 + quad * 8) = cv.v;
    }
}

__device__ __forceinline__ bf16x8 cvt8(const f32x4 a, const f32x4 b) {
    union { __hip_bfloat16 h[8]; bf16x8 v; } u;
    u.h[0] = __float2bfloat16(a.x); u.h[1] = __float2bfloat16(a.y);
    u.h[2] = __float2bfloat16(a.z); u.h[3] = __float2bfloat16(a.w);
    u.h[4] = __float2bfloat16(b.x); u.h[5] = __float2bfloat16(b.y);
    u.h[6] = __float2bfloat16(b.z); u.h[7] = __float2bfloat16(b.w);
    return u.v;
}

// ---------------------------------------------------------------------------
// Main fused kernel — 2-PHASE COUNTED-VMCNT PIPELINE (R9; T3/T4 pattern).
//  Closing the books on R0-R8: per-CU traffic (524 KB) at fair-share HBM
//  service (~10 B/cy) gives a ~20 µs floor; measured 44 = 2.2x. The 2.2x is
//  phase convoy: each block bursts its whole 32 KB x-demand, then goes
//  memory-silent. Fix = counted-vmcnt pipeline (never drain to 0 mid-block):
//   issue order per wave (all compiler-visible VMEM, pinned by "memory"
//   clobbers so the counts below are exact):
//     8x B-loads (chunks 0-3)            [oldest, 32 VGPR]
//     2x DMA x half0 (k 0..127)          [global_load_lds w=16]
//     2x DMA x half1 (k 128..255)
//     vmcnt(2)+barrier   -> B0-3 + half0 landed; HALF1 STILL IN FLIGHT
//     compute chunks 0-3; issue 8x B-loads (chunks 4-7)
//     vmcnt(8)+barrier   -> half1 landed; new B-loads in flight
//     compute chunks 4-7; epilogue
//  Half1's HBM latency hides under phase-0 compute; the read stream stays
//  live across the block's life.
//  LDS layout half-major (DMA dest is linear): addr = h*16384 + row*512 +
//  gg*16, gg in [0,32); LDS(row,gg) holds global granule h*32 + (gg&24) +
//  ((gg&7)^(row&7))  [inverse swizzle at source; read applies same XOR].
//  Read bank check: (row*32+gg)%8 = (q*2^(lm&7))&7 -> uniform 8 lanes/group.
//  Epilogue: R8's swapped-operand mfma(W,x) -> transposed C, dwordx4 stores.
// Grid: 8 g x 256 rowblocks = 2048 blocks; bid&7 = g keeps Wt[g] XCD-local.
// ---------------------------------------------------------------------------
__global__ __launch_bounds__(512, 6) void gkan_kernel(const float* __restrict__ x,
                                                      const __hip_bfloat16* __restrict__ Wt,
                                                      const float* __restrict__ bias,
                                                      const float* __restrict__ pc,
                                                      const float* __restrict__ qc,
                                                      float* __restrict__ out) {
    __shared__ __align__(16) float As[32 * 256];   // 32 KB: [half][row][512B]

    const int bid  = blockIdx.x;
    const int g    = bid & 7;
    const int row0 = (bid >> 3) * 32;

    const int t    = threadIdx.x;
    const int wave = t >> 6;             // 0..7 -> cols [wave*32, +32)
    const int lane = t & 63;
    const int lm   = lane & 15;
    const int q    = lane >> 4;

    // ---- B preload: chunks 0-3 (8 loads, OLDEST vmem) ----
    const __hip_bfloat16* bp = Wt + (size_t)g * (GIN_ * GOUT_)
                                  + (wave * 2) * 512 + lm * 32 + q * 8;
    bf16x8 B0[4], B1[4];
#pragma unroll
    for (int c = 0; c < 4; ++c) {
        B0[c] = *(const bf16x8*)(bp + (size_t)c * (16 * 512));
        B1[c] = *(const bf16x8*)(bp + (size_t)c * (16 * 512) + 512);
    }

    // ---- x slab DMA: half0 (2 instrs), then half1 (2 instrs) ----
    // instr (h,j): LDS dest = h*16384 + j*8192 + t*16 (linear)
    //   -> row = j*16 + (t>>5), in-half granule gg = t&31
    //   src granule = h*32 + (gg&24) + ((gg&7) ^ (row&7))   [inverse swizzle]
    {
        const float* xrow = x + (size_t)row0 * LDX_ + g * GIN_;
        const int rw  = t >> 5;          // 0..15
        const int g8  = t & 7;
        const int ghi = t & 24;
#pragma unroll
        for (int h = 0; h < 2; ++h)
#pragma unroll
            for (int j = 0; j < 2; ++j) {
                const int row  = j * 16 + rw;
                const int gsrc = h * 32 + ghi + (g8 ^ (row & 7));
                const float* src = xrow + (size_t)row * LDX_ + gsrc * 4;
                __builtin_amdgcn_global_load_lds(
                    (const __attribute__((address_space(1))) void*)src,
                    (__attribute__((address_space(3))) void*)
                        ((char*)As + h * 16384 + j * 8192 + t * 16),
                    16, 0, 0);
            }
    }

    // ---- phase 0 gate: B0-3 + half0 landed; half1 (2 ops) stays in flight
    asm volatile("s_waitcnt vmcnt(2)\n\ts_barrier" ::: "memory");

    // ---- phase 0: chunks 0-3 from LDS half0 ----
    f32x4 acc[2][2] = {};   // acc[mt][nt], swapped-operand (transposed C)
#pragma unroll
    for (int c = 0; c < 4; ++c) {
        bf16x8 af[2];
#pragma unroll
        for (int mt = 0; mt < 2; ++mt) {
            const int rr  = mt * 16 + lm;
            const int gg0 = c * 8 + ((q * 2)     ^ (lm & 7));
            const int gg1 = c * 8 + ((q * 2 + 1) ^ (lm & 7));
            const f32x4 lo = *(const f32x4*)((const char*)As + rr * 512 + gg0 * 16);
            const f32x4 hi = *(const f32x4*)((const char*)As + rr * 512 + gg1 * 16);
            af[mt] = cvt8(lo, hi);
        }
        acc[0][0] = __builtin_amdgcn_mfma_f32_16x16x32_bf16(B0[c], af[0], acc[0][0], 0, 0, 0);
        acc[0][1] = __builtin_amdgcn_mfma_f32_16x16x32_bf16(B1[c], af[0], acc[0][1], 0, 0, 0);
        acc[1][0] = __builtin_amdgcn_mfma_f32_16x16x32_bf16(B0[c], af[1], acc[1][0], 0, 0, 0);
        acc[1][1] = __builtin_amdgcn_mfma_f32_16x16x32_bf16(B1[c], af[1], acc[1][1], 0, 0, 0);
    }

    // ---- issue B for chunks 4-7 (8 loads; stay in flight across the gate)
#pragma unroll
    for (int c = 0; c < 4; ++c) {
        B0[c] = *(const bf16x8*)(bp + (size_t)(c + 4) * (16 * 512));
        B1[c] = *(const bf16x8*)(bp + (size_t)(c + 4) * (16 * 512) + 512);
    }

    // ---- phase 1 gate: half1 landed (8 young B-loads may be outstanding)
    asm volatile("s_waitcnt vmcnt(8)\n\ts_barrier" ::: "memory");

    // ---- phase 1: chunks 4-7 from LDS half1 ----
#pragma unroll
    for (int c = 0; c < 4; ++c) {
        bf16x8 af[2];
#pragma unroll
        for (int mt = 0; mt < 2; ++mt) {
            const int rr  = mt * 16 + lm;
            const int gg0 = c * 8 + ((q * 2)     ^ (lm & 7));
            const int gg1 = c * 8 + ((q * 2 + 1) ^ (lm & 7));
            const f32x4 lo = *(const f32x4*)((const char*)As + 16384 + rr * 512 + gg0 * 16);
            const f32x4 hi = *(const f32x4*)((const char*)As + 16384 + rr * 512 + gg1 * 16);
            af[mt] = cvt8(lo, hi);
        }
        acc[0][0] = __builtin_amdgcn_mfma_f32_16x16x32_bf16(B0[c], af[0], acc[0][0], 0, 0, 0);
        acc[0][1] = __builtin_amdgcn_mfma_f32_16x16x32_bf16(B1[c], af[0], acc[0][1], 0, 0, 0);
        acc[1][0] = __builtin_amdgcn_mfma_f32_16x16x32_bf16(B0[c], af[1], acc[1][0], 0, 0, 0);
        acc[1][1] = __builtin_amdgcn_mfma_f32_16x16x32_bf16(B1[c], af[1], acc[1][1], 0, 0, 0);
    }

    // ---- epilogue consts (after the pipeline; not live in-loop) ----
    const float p0 = pc[g * 4 + 0], p1 = pc[g * 4 + 1];
    const float p2 = pc[g * 4 + 2], p3 = pc[g * 4 + 3];
    const float q0 = qc[g * 3 + 0], q1 = qc[g * 3 + 1], q2 = qc[g * 3 + 2];

    // ---- epilogue: transposed-C -> lane lm = out-row, reg r = 4 consecutive
    //      cols. ONE dwordx4 store per (mt,nt). ----
#pragma unroll
    for (int mt = 0; mt < 2; ++mt) {
        const int row_o = row0 + mt * 16 + lm;
#pragma unroll
        for (int nt = 0; nt < 2; ++nt) {
            const int col0 = g * GOUT_ + wave * 32 + nt * 16 + q * 4;
            const f32x4 bb4 = *(const f32x4*)(bias + col0);
            f32x4 o;
#pragma unroll
            for (int r = 0; r < 4; ++r) {
                const float y   = acc[mt][nt][r] + bb4[r];
                const float num = p0 + y * (p1 + y * (p2 + y * p3));
                const float den = 1.0f + fabsf(y * (q0 + y * (q1 + y * q2)));
                o[r] = num * __builtin_amdgcn_rcpf(den);
            }
            *(f32x4*)(out + (size_t)row_o * LDX_ + col0) = o;
        }
    }
}

extern "C" void kernel_launch(void* const* d_in, const int* in_sizes, int n_in,
                              void* d_out, int out_size, void* d_ws, size_t ws_size,
                              hipStream_t stream) {
    const float* x = (const float*)d_in[0];
    const float* W = (const float*)d_in[1];
    const float* b = (const float*)d_in[2];
    const float* p = (const float*)d_in[3];
    const float* q = (const float*)d_in[4];
    float* out = (float*)d_out;

    __hip_bfloat16* Wt = (__hip_bfloat16*)d_ws;   // 1 MiB fragment-tiled bf16 W

    wprep_kernel<<<128, 256, 0, stream>>>(W, Wt);
    gkan_kernel<<<2048, 512, 0, stream>>>(x, Wt, b, p, q, out);
}